// Round 20
// baseline (303.848 us; speedup 1.0000x reference)
//
#include <hip/hip_runtime.h>
#include <hip/hip_bf16.h>

typedef short bf16x8 __attribute__((ext_vector_type(8)));
typedef float f32x4 __attribute__((ext_vector_type(4)));

#define B_TOT 32768
#define ROWS  128           // 16 batches per WG
#define NTHR  512           // 8 waves; wave w owns rows 16w..16w+15

// ---- workspace layout (elements): bf16 W^T, written by prep_w each call ----
#define WSQ_ELT  0          // ushort [384][256]  qkv_w^T
#define WSP_ELT  98304      // ushort [256][128]  proj_w^T

// ---- main-kernel LDS layout (bytes) — EXACT r15/r19 skeleton ----
#define WQ0_OFF  0          // ushort[96][64]  12288
#define WQ1_OFF  12288      // ushort[96][64]  12288
#define QK_OFF   24576      // ushort[128][104] 26624 ; chunk f32[128][68]=34816 overlays
#define QK_STR   104
#define CH_STR   68
#define BIAS_OFF 59392      // float[8][8][5]    1280
#define PB_OFF   60672      // float[256]        1024
#define LDS_BYTES 61696     // 2 WG/CU by LDS

static __device__ __forceinline__ unsigned short f2b(float f) {
    __hip_bfloat16 h = __float2bfloat16(f);
    return reinterpret_cast<unsigned short&>(h);
}
static __device__ __forceinline__ float b2f(unsigned short u) {
    union { unsigned u; float f; } v; v.u = ((unsigned)u) << 16; return v.f;
}
static __device__ __forceinline__ void gload_lds16(const unsigned short* g, unsigned short* l) {
    __builtin_amdgcn_global_load_lds(
        (const __attribute__((address_space(1))) unsigned int*)g,
        (__attribute__((address_space(3))) unsigned int*)l, 16, 0, 0);
}
// Force a 128-bit MFMA-operand value into the AGPR half of the unified RF.
// gfx950 MFMA reads A/B from AGPR directly (AV class), so no copies result;
// arch-VGPR pressure drops and the scratch spill disappears.
static __device__ __forceinline__ void to_agpr(bf16x8& v) {
    asm volatile("" : "+a"(v));
}

// ---------- pre-kernel: W (f32, row-major) -> W^T (bf16) in ws ----------
__global__ __launch_bounds__(256)
void prep_w(const float* __restrict__ qkv_w, const float* __restrict__ proj_w,
            unsigned short* __restrict__ ws)
{
    __shared__ float tile[64][65];
    const int bid = blockIdx.x;
    const float* src; unsigned short* dst; int ldw, ldk, tr0, tc0;
    if (bid < 24) {
        int kr = bid / 6, cg = bid % 6;
        src = qkv_w; dst = ws + WSQ_ELT; ldw = 384; ldk = 256;
        tr0 = kr * 64; tc0 = cg * 64;
    } else {
        int b = bid - 24; int kr = b / 4, cg = b % 4;
        src = proj_w; dst = ws + WSP_ELT; ldw = 256; ldk = 128;
        tr0 = kr * 64; tc0 = cg * 64;
    }
    const int t = threadIdx.x;
    #pragma unroll
    for (int i = 0; i < 16; ++i) {
        int idx = i * 256 + t;
        int r = idx >> 6, c = idx & 63;
        tile[r][c] = src[(size_t)(tr0 + r) * ldw + tc0 + c];
    }
    __syncthreads();
    #pragma unroll
    for (int i = 0; i < 2; ++i) {
        int idx = i * 256 + t;
        int c = idx >> 3, r0 = (idx & 7) * 8;
        union { unsigned short u[8]; uint4 v; } pk;
        #pragma unroll
        for (int j = 0; j < 8; ++j) pk.u[j] = f2b(tile[r0 + j][c]);
        *(uint4*)&dst[(size_t)(tc0 + c) * ldk + tr0 + r0] = pk.v;
    }
}

// ---------- main fused kernel: r19 + AGPR placement for MFMA operands ----------
__global__ __launch_bounds__(NTHR, 4)
void ta_fused(const float* __restrict__ x,
              const unsigned short* __restrict__ ws,
              const float* __restrict__ proj_b,
              const float* __restrict__ bias_table,
              const int* __restrict__ rel_index,
              float* __restrict__ out)
{
    __shared__ __align__(16) char smem[LDS_BYTES];
    unsigned short* wq0 = (unsigned short*)(smem + WQ0_OFF);
    unsigned short* wq1 = (unsigned short*)(smem + WQ1_OFF);
    unsigned short* qks = (unsigned short*)(smem + QK_OFF);
    float* chunk  = (float*)(smem + QK_OFF);      // overlays qks (dead in GEMM2)
    float* bias_s = (float*)(smem + BIAS_OFF);
    float* pbs    = (float*)(smem + PB_OFF);

    const unsigned short* wsq = ws + WSQ_ELT;
    const unsigned short* wsp = ws + WSP_ELT;

    const int tid = threadIdx.x;
    const int l   = tid & 63;
    const int w   = tid >> 6;          // 0..7
    const int l15 = l & 15;
    const int l4  = l >> 4;
    const long wg = blockIdx.x;

    // stage one GEMM1 K=64 slice of head h, quarter c2 (96 rows x 64 k)
    auto stage1 = [&](int h, int c2, unsigned short* buf) {
        {
            int rr = tid >> 3, seg = tid & 7;           // idx 0..511 (q+k rows)
            int p = rr >> 5, wi = rr & 31;
            gload_lds16(&wsq[(size_t)(p * 128 + h * 32 + wi) * 256 + c2 * 64
                             + ((seg ^ (rr & 7)) << 3)],
                        &buf[rr * 64 + seg * 8]);
        }
        if (tid < 256) {                                 // idx 512..767 (v rows)
            int idx = NTHR + tid;
            int rr = idx >> 3, seg = idx & 7;
            int p = rr >> 5, wi = rr & 31;
            gload_lds16(&wsq[(size_t)(p * 128 + h * 32 + wi) * 256 + c2 * 64
                             + ((seg ^ (rr & 7)) << 3)],
                        &buf[rr * 64 + seg * 8]);
        }
    };
    // stage one GEMM2 K=64 slice: 64 rows (cols cc*64..) x 64 k
    auto stage2 = [&](int cc, int kh, unsigned short* buf) {
        int rr = tid >> 3, seg = tid & 7;                // exactly 512 slots
        gload_lds16(&wsp[(size_t)(cc * 64 + rr) * 128 + kh * 64
                         + ((seg ^ (rr & 7)) << 3)],
                    &buf[rr * 64 + seg * 8]);
    };

    // ---- prologue: stage phase 0 first (loads lead), then x frags, tables ----
    stage1(0, 0, wq0);

    bf16x8 af[8];
    {
        const float* xr = x + wg * (size_t)(ROWS * 256) + (size_t)(16 * w + l15) * 256;
        #pragma unroll
        for (int s = 0; s < 8; ++s) {
            f32x4 d0 = *(const f32x4*)(xr + s * 32 + l4 * 8);
            f32x4 d1 = *(const f32x4*)(xr + s * 32 + l4 * 8 + 4);
            union { unsigned short u[8]; bf16x8 v; } pk;
            #pragma unroll
            for (int j = 0; j < 4; ++j) pk.u[j] = f2b(d0[j]);
            #pragma unroll
            for (int j = 0; j < 4; ++j) pk.u[4 + j] = f2b(d1[j]);
            af[s] = pk.v;
            to_agpr(af[s]);            // park x-fragments in the acc file
        }
    }
    if (tid < 256) {
        int n = tid >> 5, m = (tid >> 2) & 7, hh = tid & 3;
        int ri = rel_index[n * 8 + m];
        bias_s[n * 40 + m * 5 + hh] = bias_table[ri * 4 + hh];
        pbs[tid] = proj_b[tid];
    }

    bf16x8 of0, of1, of2, of3;
    const f32x4 zero4 = {0.f, 0.f, 0.f, 0.f};

    // ---- GEMM1: 16 pipelined phases (h, c2), 1 barrier each ----
    #pragma unroll 1
    for (int h = 0; h < 4; ++h) {
        f32x4 acc[6];
        #pragma unroll
        for (int i = 0; i < 6; ++i) acc[i] = zero4;

        #pragma unroll
        for (int c2 = 0; c2 < 4; ++c2) {               // phase parity = c2&1
            unsigned short* cur = (c2 & 1) ? wq1 : wq0;
            unsigned short* nxt = (c2 & 1) ? wq0 : wq1;
            __syncthreads();                           // drains vmcnt: cur ready
            if (c2 < 3)      stage1(h, c2 + 1, nxt);   // issue-early
            else if (h < 3)  stage1(h + 1, 0, nxt);
            else             stage2(0, 0, nxt);        // hides under attention h=3
            __builtin_amdgcn_s_setprio(1);             // T5
            #pragma unroll
            for (int ks2 = 0; ks2 < 2; ++ks2) {
                bf16x8 a = af[c2 * 2 + ks2];
                #pragma unroll
                for (int ct = 0; ct < 6; ++ct) {
                    int brow = ct * 16 + l15;
                    bf16x8 b = *(bf16x8*)&cur[brow * 64 + (((ks2 * 4 + l4) ^ (brow & 7)) << 3)];
                    // swapped: D[m=channel][n=batch]; lane holds one batch-row,
                    // 4 consecutive channels
                    acc[ct] = __builtin_amdgcn_mfma_f32_16x16x32_bf16(b, a, acc[ct], 0, 0, 0);
                }
            }
            __builtin_amdgcn_s_setprio(0);
        }
        // qkv -> wave-private qks rows: 6 x b64 packed-channel writes (no barrier)
        {
            int row = 16 * w + l15;
            #pragma unroll
            for (int ct = 0; ct < 6; ++ct) {
                union { unsigned short u[4]; uint2 v; } pk;
                #pragma unroll
                for (int j = 0; j < 4; ++j) pk.u[j] = f2b(acc[ct][j]);
                *(uint2*)&qks[row * QK_STR + ct * 16 + l4 * 4] = pk.v;
            }
        }

        // ---- attention (head h): barrier-free, wave-private ----
        {
            const int r  = 16 * w + l15;
            const int rb = r & ~7;
            const int n  = r & 7;
            float qf[8];
            {
                bf16x8 qv = *(bf16x8*)&qks[r * QK_STR + l4 * 8];
                #pragma unroll
                for (int j = 0; j < 8; ++j) qf[j] = b2f((unsigned short)qv[j]);
            }
            float sp[8];
            #pragma unroll
            for (int m = 0; m < 8; ++m) {
                bf16x8 kv = *(bf16x8*)&qks[(rb + m) * QK_STR + 32 + l4 * 8];
                float s = 0.f;
                #pragma unroll
                for (int j = 0; j < 8; ++j) s += qf[j] * b2f((unsigned short)kv[j]);
                sp[m] = s;
            }
            #pragma unroll
            for (int m = 0; m < 8; ++m) {
                sp[m] += __shfl_xor(sp[m], 16);
                sp[m] += __shfl_xor(sp[m], 32);
            }
            float mx = -1e30f;
            #pragma unroll
            for (int m = 0; m < 8; ++m) {
                sp[m] = sp[m] * 0.125f + bias_s[n * 40 + m * 5 + h];
                mx = fmaxf(mx, sp[m]);
            }
            float sum = 0.f;
            #pragma unroll
            for (int m = 0; m < 8; ++m) { sp[m] = __expf(sp[m] - mx); sum += sp[m]; }
            float inv = 1.f / sum;
            float o[8] = {0.f,0.f,0.f,0.f,0.f,0.f,0.f,0.f};
            #pragma unroll
            for (int m = 0; m < 8; ++m) {
                bf16x8 vv = *(bf16x8*)&qks[(rb + m) * QK_STR + 64 + l4 * 8];
                #pragma unroll
                for (int j = 0; j < 8; ++j) o[j] += sp[m] * b2f((unsigned short)vv[j]);
            }
            bf16x8 ofr;
            #pragma unroll
            for (int j = 0; j < 8; ++j) ofr[j] = (short)f2b(o[j] * inv);
            if      (h == 0) { of0 = ofr; to_agpr(of0); }   // park in acc file
            else if (h == 1) { of1 = ofr; to_agpr(of1); }
            else if (h == 2) { of2 = ofr; to_agpr(of2); }
            else             { of3 = ofr; to_agpr(of3); }
        }
    }

    // ---- GEMM2: pipelined staging + r15's barriered chunk epilogue ----
    #pragma unroll 1
    for (int cc = 0; cc < 4; ++cc) {
        __syncthreads();                       // wq0 ready (staged prev phase);
                                               // also: prev copy's chunk readers done
        stage2(cc, 1, wq1);                    // issue kh=1 slice

        f32x4 acc2[4];
        #pragma unroll
        for (int i = 0; i < 4; ++i) acc2[i] = zero4;
        __builtin_amdgcn_s_setprio(1);
        #pragma unroll
        for (int ks = 0; ks < 2; ++ks) {
            bf16x8 b = (ks == 0) ? of0 : of1;  // heads 0,1 (k 0..63)
            #pragma unroll
            for (int ctl = 0; ctl < 4; ++ctl) {
                int brow = ctl * 16 + l15;
                bf16x8 a = *(bf16x8*)&wq0[brow * 64 + (((ks * 4 + l4) ^ (brow & 7)) << 3)];
                acc2[ctl] = __builtin_amdgcn_mfma_f32_16x16x32_bf16(a, b, acc2[ctl], 0, 0, 0);
            }
        }
        __builtin_amdgcn_s_setprio(0);
        __syncthreads();                       // wq1 ready
        if (cc < 3) stage2(cc + 1, 0, wq0);    // issue next cc's first slice
        __builtin_amdgcn_s_setprio(1);
        #pragma unroll
        for (int ks = 0; ks < 2; ++ks) {
            bf16x8 b = (ks == 0) ? of2 : of3;  // heads 2,3 (k 64..127)
            #pragma unroll
            for (int ctl = 0; ctl < 4; ++ctl) {
                int brow = ctl * 16 + l15;
                bf16x8 a = *(bf16x8*)&wq1[brow * 64 + (((ks * 4 + l4) ^ (brow & 7)) << 3)];
                acc2[ctl] = __builtin_amdgcn_mfma_f32_16x16x32_bf16(a, b, acc2[ctl], 0, 0, 0);
            }
        }
        __builtin_amdgcn_s_setprio(0);
        // epilogue: lane holds out[row=16w+l15][4 consecutive cols] -> b128 chunk writes
        {
            int row = 16 * w + l15;
            #pragma unroll
            for (int ctl = 0; ctl < 4; ++ctl) {
                int colb = ctl * 16 + l4 * 4;
                f32x4 pb4 = *(f32x4*)&pbs[cc * 64 + colb];
                f32x4 v;
                #pragma unroll
                for (int j = 0; j < 4; ++j) v[j] = acc2[ctl][j] + pb4[j];
                *(f32x4*)&chunk[row * CH_STR + colb] = v;
            }
        }
        __syncthreads();                       // chunk complete
        // copy chunk -> global, fully coalesced
        {
            float* og = out + wg * (size_t)(ROWS * 256) + cc * 64;
            #pragma unroll
            for (int i = 0; i < 4; ++i) {
                int f0 = i * NTHR + tid;          // 0..2047 f32x4-chunks
                int row = f0 >> 4, c4 = f0 & 15;
                f32x4 v = *(f32x4*)&chunk[row * CH_STR + c4 * 4];
                *(f32x4*)(og + (size_t)row * 256 + c4 * 4) = v;
            }
        }
    }
}

extern "C" void kernel_launch(void* const* d_in, const int* in_sizes, int n_in,
                              void* d_out, int out_size, void* d_ws, size_t ws_size,
                              hipStream_t stream)
{
    (void)in_sizes; (void)n_in; (void)ws_size; (void)out_size;
    const float* x  = (const float*)d_in[0];
    const float* qw = (const float*)d_in[1];
    const float* pw = (const float*)d_in[2];
    const float* pb = (const float*)d_in[3];
    const float* bt = (const float*)d_in[4];
    const int*   ri = (const int*)d_in[5];
    float* o = (float*)d_out;
    unsigned short* ws = (unsigned short*)d_ws;

    hipLaunchKernelGGL(prep_w, dim3(32), dim3(256), 0, stream, qw, pw, ws);
    hipLaunchKernelGGL(ta_fused, dim3(B_TOT / 16), dim3(NTHR), 0, stream,
                       x, ws, pb, bt, ri, o);
}

// Round 21
// 202.171 us; speedup vs baseline: 1.5029x; 1.5029x over previous
//
#include <hip/hip_runtime.h>
#include <hip/hip_bf16.h>

typedef short bf16x8 __attribute__((ext_vector_type(8)));
typedef float f32x4 __attribute__((ext_vector_type(4)));

#define B_TOT 32768
#define ROWS  128           // 16 batches per WG
#define NTHR  512           // 8 waves; wave w owns rows 16w..16w+15

// ---- workspace layout (elements): bf16 W^T, written by prep_w each call ----
#define WSQ_ELT  0          // ushort [384][256]  qkv_w^T
#define WSP_ELT  98304      // ushort [256][128]  proj_w^T

// ---- main-kernel LDS layout (bytes) — r15/r19 skeleton (HW-validated sync) ----
#define WQ0_OFF  0          // ushort[96][64]  12288
#define WQ1_OFF  12288      // ushort[96][64]  12288
#define QK_OFF   24576      // ushort[128][104] 26624 ; chunk f32[128][68]=34816 overlays
#define QK_STR   104
#define CH_STR   68
#define BIAS_OFF 59392      // float[8][8][5]    1280
#define PB_OFF   60672      // float[256]        1024
#define LDS_BYTES 61696     // 2 WG/CU by LDS

static __device__ __forceinline__ unsigned short f2b(float f) {
    __hip_bfloat16 h = __float2bfloat16(f);
    return reinterpret_cast<unsigned short&>(h);
}
static __device__ __forceinline__ float b2f(unsigned short u) {
    union { unsigned u; float f; } v; v.u = ((unsigned)u) << 16; return v.f;
}
static __device__ __forceinline__ void gload_lds16(const unsigned short* g, unsigned short* l) {
    __builtin_amdgcn_global_load_lds(
        (const __attribute__((address_space(1))) unsigned int*)g,
        (__attribute__((address_space(3))) unsigned int*)l, 16, 0, 0);
}

// ---------- pre-kernel: W (f32, row-major) -> W^T (bf16) in ws ----------
__global__ __launch_bounds__(256)
void prep_w(const float* __restrict__ qkv_w, const float* __restrict__ proj_w,
            unsigned short* __restrict__ ws)
{
    __shared__ float tile[64][65];
    const int bid = blockIdx.x;
    const float* src; unsigned short* dst; int ldw, ldk, tr0, tc0;
    if (bid < 24) {
        int kr = bid / 6, cg = bid % 6;
        src = qkv_w; dst = ws + WSQ_ELT; ldw = 384; ldk = 256;
        tr0 = kr * 64; tc0 = cg * 64;
    } else {
        int b = bid - 24; int kr = b / 4, cg = b % 4;
        src = proj_w; dst = ws + WSP_ELT; ldw = 256; ldk = 128;
        tr0 = kr * 64; tc0 = cg * 64;
    }
    const int t = threadIdx.x;
    #pragma unroll
    for (int i = 0; i < 16; ++i) {
        int idx = i * 256 + t;
        int r = idx >> 6, c = idx & 63;
        tile[r][c] = src[(size_t)(tr0 + r) * ldw + tc0 + c];
    }
    __syncthreads();
    #pragma unroll
    for (int i = 0; i < 2; ++i) {
        int idx = i * 256 + t;
        int c = idx >> 3, r0 = (idx & 7) * 8;
        union { unsigned short u[8]; uint4 v; } pk;
        #pragma unroll
        for (int j = 0; j < 8; ++j) pk.u[j] = f2b(tile[r0 + j][c]);
        *(uint4*)&dst[(size_t)(tc0 + c) * ldk + tr0 + r0] = pk.v;
    }
}

// ---------- main fused kernel: r19 (session optimum, reverted from r20) ----------
__global__ __launch_bounds__(NTHR, 4)
void ta_fused(const float* __restrict__ x,
              const unsigned short* __restrict__ ws,
              const float* __restrict__ proj_b,
              const float* __restrict__ bias_table,
              const int* __restrict__ rel_index,
              float* __restrict__ out)
{
    __shared__ __align__(16) char smem[LDS_BYTES];
    unsigned short* wq0 = (unsigned short*)(smem + WQ0_OFF);
    unsigned short* wq1 = (unsigned short*)(smem + WQ1_OFF);
    unsigned short* qks = (unsigned short*)(smem + QK_OFF);
    float* chunk  = (float*)(smem + QK_OFF);      // overlays qks (dead in GEMM2)
    float* bias_s = (float*)(smem + BIAS_OFF);
    float* pbs    = (float*)(smem + PB_OFF);

    const unsigned short* wsq = ws + WSQ_ELT;
    const unsigned short* wsp = ws + WSP_ELT;

    const int tid = threadIdx.x;
    const int l   = tid & 63;
    const int w   = tid >> 6;          // 0..7
    const int l15 = l & 15;
    const int l4  = l >> 4;
    const long wg = blockIdx.x;

    // stage one GEMM1 K=64 slice of head h, quarter c2 (96 rows x 64 k)
    auto stage1 = [&](int h, int c2, unsigned short* buf) {
        {
            int rr = tid >> 3, seg = tid & 7;           // idx 0..511 (q+k rows)
            int p = rr >> 5, wi = rr & 31;
            gload_lds16(&wsq[(size_t)(p * 128 + h * 32 + wi) * 256 + c2 * 64
                             + ((seg ^ (rr & 7)) << 3)],
                        &buf[rr * 64 + seg * 8]);
        }
        if (tid < 256) {                                 // idx 512..767 (v rows)
            int idx = NTHR + tid;
            int rr = idx >> 3, seg = idx & 7;
            int p = rr >> 5, wi = rr & 31;
            gload_lds16(&wsq[(size_t)(p * 128 + h * 32 + wi) * 256 + c2 * 64
                             + ((seg ^ (rr & 7)) << 3)],
                        &buf[rr * 64 + seg * 8]);
        }
    };
    // stage one GEMM2 K=64 slice: 64 rows (cols cc*64..) x 64 k
    auto stage2 = [&](int cc, int kh, unsigned short* buf) {
        int rr = tid >> 3, seg = tid & 7;                // exactly 512 slots
        gload_lds16(&wsp[(size_t)(cc * 64 + rr) * 128 + kh * 64
                         + ((seg ^ (rr & 7)) << 3)],
                    &buf[rr * 64 + seg * 8]);
    };

    // ---- prologue: stage phase 0 first (loads lead), then x frags, tables ----
    stage1(0, 0, wq0);

    bf16x8 af[8];
    {
        const float* xr = x + wg * (size_t)(ROWS * 256) + (size_t)(16 * w + l15) * 256;
        #pragma unroll
        for (int s = 0; s < 8; ++s) {
            f32x4 d0 = *(const f32x4*)(xr + s * 32 + l4 * 8);
            f32x4 d1 = *(const f32x4*)(xr + s * 32 + l4 * 8 + 4);
            union { unsigned short u[8]; bf16x8 v; } pk;
            #pragma unroll
            for (int j = 0; j < 4; ++j) pk.u[j] = f2b(d0[j]);
            #pragma unroll
            for (int j = 0; j < 4; ++j) pk.u[4 + j] = f2b(d1[j]);
            af[s] = pk.v;
        }
    }
    if (tid < 256) {
        int n = tid >> 5, m = (tid >> 2) & 7, hh = tid & 3;
        int ri = rel_index[n * 8 + m];
        bias_s[n * 40 + m * 5 + hh] = bias_table[ri * 4 + hh];
        pbs[tid] = proj_b[tid];
    }

    bf16x8 of0, of1, of2, of3;
    const f32x4 zero4 = {0.f, 0.f, 0.f, 0.f};

    // ---- GEMM1: 16 pipelined phases (h, c2), 1 barrier each ----
    #pragma unroll 1
    for (int h = 0; h < 4; ++h) {
        f32x4 acc[6];
        #pragma unroll
        for (int i = 0; i < 6; ++i) acc[i] = zero4;

        #pragma unroll
        for (int c2 = 0; c2 < 4; ++c2) {               // phase parity = c2&1
            unsigned short* cur = (c2 & 1) ? wq1 : wq0;
            unsigned short* nxt = (c2 & 1) ? wq0 : wq1;
            __syncthreads();                           // drains vmcnt: cur ready
            if (c2 < 3)      stage1(h, c2 + 1, nxt);   // issue-early
            else if (h < 3)  stage1(h + 1, 0, nxt);
            else             stage2(0, 0, nxt);        // hides under attention h=3
            __builtin_amdgcn_s_setprio(1);             // T5
            #pragma unroll
            for (int ks2 = 0; ks2 < 2; ++ks2) {
                bf16x8 a = af[c2 * 2 + ks2];
                #pragma unroll
                for (int ct = 0; ct < 6; ++ct) {
                    int brow = ct * 16 + l15;
                    bf16x8 b = *(bf16x8*)&cur[brow * 64 + (((ks2 * 4 + l4) ^ (brow & 7)) << 3)];
                    // swapped: D[m=channel][n=batch]; lane holds one batch-row,
                    // 4 consecutive channels
                    acc[ct] = __builtin_amdgcn_mfma_f32_16x16x32_bf16(b, a, acc[ct], 0, 0, 0);
                }
            }
            __builtin_amdgcn_s_setprio(0);
        }
        // qkv -> wave-private qks rows: 6 x b64 packed-channel writes (no barrier)
        {
            int row = 16 * w + l15;
            #pragma unroll
            for (int ct = 0; ct < 6; ++ct) {
                union { unsigned short u[4]; uint2 v; } pk;
                #pragma unroll
                for (int j = 0; j < 4; ++j) pk.u[j] = f2b(acc[ct][j]);
                *(uint2*)&qks[row * QK_STR + ct * 16 + l4 * 4] = pk.v;
            }
        }

        // ---- attention (head h): barrier-free, wave-private ----
        {
            const int r  = 16 * w + l15;
            const int rb = r & ~7;
            const int n  = r & 7;
            float qf[8];
            {
                bf16x8 qv = *(bf16x8*)&qks[r * QK_STR + l4 * 8];
                #pragma unroll
                for (int j = 0; j < 8; ++j) qf[j] = b2f((unsigned short)qv[j]);
            }
            float sp[8];
            #pragma unroll
            for (int m = 0; m < 8; ++m) {
                bf16x8 kv = *(bf16x8*)&qks[(rb + m) * QK_STR + 32 + l4 * 8];
                float s = 0.f;
                #pragma unroll
                for (int j = 0; j < 8; ++j) s += qf[j] * b2f((unsigned short)kv[j]);
                sp[m] = s;
            }
            #pragma unroll
            for (int m = 0; m < 8; ++m) {
                sp[m] += __shfl_xor(sp[m], 16);
                sp[m] += __shfl_xor(sp[m], 32);
            }
            float mx = -1e30f;
            #pragma unroll
            for (int m = 0; m < 8; ++m) {
                sp[m] = sp[m] * 0.125f + bias_s[n * 40 + m * 5 + h];
                mx = fmaxf(mx, sp[m]);
            }
            float sum = 0.f;
            #pragma unroll
            for (int m = 0; m < 8; ++m) { sp[m] = __expf(sp[m] - mx); sum += sp[m]; }
            float inv = 1.f / sum;
            float o[8] = {0.f,0.f,0.f,0.f,0.f,0.f,0.f,0.f};
            #pragma unroll
            for (int m = 0; m < 8; ++m) {
                bf16x8 vv = *(bf16x8*)&qks[(rb + m) * QK_STR + 64 + l4 * 8];
                #pragma unroll
                for (int j = 0; j < 8; ++j) o[j] += sp[m] * b2f((unsigned short)vv[j]);
            }
            bf16x8 ofr;
            #pragma unroll
            for (int j = 0; j < 8; ++j) ofr[j] = (short)f2b(o[j] * inv);
            if      (h == 0) of0 = ofr;
            else if (h == 1) of1 = ofr;
            else if (h == 2) of2 = ofr;
            else             of3 = ofr;
        }
    }

    // ---- GEMM2: pipelined staging + barriered chunk epilogue ----
    #pragma unroll 1
    for (int cc = 0; cc < 4; ++cc) {
        __syncthreads();                       // wq0 ready (staged prev phase);
                                               // also: prev copy's chunk readers done
        stage2(cc, 1, wq1);                    // issue kh=1 slice

        f32x4 acc2[4];
        #pragma unroll
        for (int i = 0; i < 4; ++i) acc2[i] = zero4;
        __builtin_amdgcn_s_setprio(1);
        #pragma unroll
        for (int ks = 0; ks < 2; ++ks) {
            bf16x8 b = (ks == 0) ? of0 : of1;  // heads 0,1 (k 0..63)
            #pragma unroll
            for (int ctl = 0; ctl < 4; ++ctl) {
                int brow = ctl * 16 + l15;
                bf16x8 a = *(bf16x8*)&wq0[brow * 64 + (((ks * 4 + l4) ^ (brow & 7)) << 3)];
                acc2[ctl] = __builtin_amdgcn_mfma_f32_16x16x32_bf16(a, b, acc2[ctl], 0, 0, 0);
            }
        }
        __builtin_amdgcn_s_setprio(0);
        __syncthreads();                       // wq1 ready
        if (cc < 3) stage2(cc + 1, 0, wq0);    // issue next cc's first slice
        __builtin_amdgcn_s_setprio(1);
        #pragma unroll
        for (int ks = 0; ks < 2; ++ks) {
            bf16x8 b = (ks == 0) ? of2 : of3;  // heads 2,3 (k 64..127)
            #pragma unroll
            for (int ctl = 0; ctl < 4; ++ctl) {
                int brow = ctl * 16 + l15;
                bf16x8 a = *(bf16x8*)&wq1[brow * 64 + (((ks * 4 + l4) ^ (brow & 7)) << 3)];
                acc2[ctl] = __builtin_amdgcn_mfma_f32_16x16x32_bf16(a, b, acc2[ctl], 0, 0, 0);
            }
        }
        __builtin_amdgcn_s_setprio(0);
        // epilogue: lane holds out[row=16w+l15][4 consecutive cols] -> b128 chunk writes
        {
            int row = 16 * w + l15;
            #pragma unroll
            for (int ctl = 0; ctl < 4; ++ctl) {
                int colb = ctl * 16 + l4 * 4;
                f32x4 pb4 = *(f32x4*)&pbs[cc * 64 + colb];
                f32x4 v;
                #pragma unroll
                for (int j = 0; j < 4; ++j) v[j] = acc2[ctl][j] + pb4[j];
                *(f32x4*)&chunk[row * CH_STR + colb] = v;
            }
        }
        __syncthreads();                       // chunk complete
        // copy chunk -> global, fully coalesced
        {
            float* og = out + wg * (size_t)(ROWS * 256) + cc * 64;
            #pragma unroll
            for (int i = 0; i < 4; ++i) {
                int f0 = i * NTHR + tid;          // 0..2047 f32x4-chunks
                int row = f0 >> 4, c4 = f0 & 15;
                f32x4 v = *(f32x4*)&chunk[row * CH_STR + c4 * 4];
                *(f32x4*)(og + (size_t)row * 256 + c4 * 4) = v;
            }
        }
    }
}

extern "C" void kernel_launch(void* const* d_in, const int* in_sizes, int n_in,
                              void* d_out, int out_size, void* d_ws, size_t ws_size,
                              hipStream_t stream)
{
    (void)in_sizes; (void)n_in; (void)ws_size; (void)out_size;
    const float* x  = (const float*)d_in[0];
    const float* qw = (const float*)d_in[1];
    const float* pw = (const float*)d_in[2];
    const float* pb = (const float*)d_in[3];
    const float* bt = (const float*)d_in[4];
    const int*   ri = (const int*)d_in[5];
    float* o = (float*)d_out;
    unsigned short* ws = (unsigned short*)d_ws;

    hipLaunchKernelGGL(prep_w, dim3(32), dim3(256), 0, stream, qw, pw, ws);
    hipLaunchKernelGGL(ta_fused, dim3(B_TOT / 16), dim3(NTHR), 0, stream,
                       x, ws, pb, bt, ri, o);
}